// Round 1
// baseline (1083.163 us; speedup 1.0000x reference)
//
#include <hip/hip_runtime.h>
#include <hip/hip_bf16.h>
#include <math.h>

#define NPIX 262144          // 512*512
#define PI_D 3.14159265358979323846264338327950288

// ---------------- ws layout (byte offsets) ----------------
// 0      : double stats[2]        (mean_t, template_var)
// 64     : double den[32][121]
// 31744  : double snn[32]
// 32000  : double shx[32]
// 32256  : double shy[32]
// 32512  : float  c2[32]
// 32768  : float  partial[32][8][121]
// 157696 : float  ary[32][512]
// 223232 : float  arx[32][512]
// 524288 : float  yt[cb][512][512]

// K1: template mean & variance (double)
__global__ __launch_bounds__(256) void k_template_stats(const float* __restrict__ t, double* __restrict__ stats){
    double s = 0.0, s2 = 0.0;
    for (int i = threadIdx.x; i < NPIX; i += 256){ double v = t[i]; s += v; s2 += v*v; }
    __shared__ double rs[256], rs2[256];
    rs[threadIdx.x] = s; rs2[threadIdx.x] = s2; __syncthreads();
    for (int off = 128; off > 0; off >>= 1){
        if (threadIdx.x < off){ rs[threadIdx.x] += rs[threadIdx.x+off]; rs2[threadIdx.x] += rs2[threadIdx.x+off]; }
        __syncthreads();
    }
    if (threadIdx.x == 0){
        double mean = rs[0] / (double)NPIX;
        stats[0] = mean;
        stats[1] = rs2[0] - rs[0]*rs[0]/(double)NPIX + 1e-8;   // sum((t-mean)^2) + EPS
    }
}

// K2: 502x502 window sums -> denominator[b][u][v] (double)
__global__ __launch_bounds__(256) void k_winsums(const float* __restrict__ fr, const double* __restrict__ stats,
                                                 double* __restrict__ den){
    int b = blockIdx.x / 11, u = blockIdx.x % 11;
    const float* img = fr + (size_t)b * NPIX;
    int c0 = threadIdx.x, c1 = threadIdx.x + 256;
    float a0=0.f, a1=0.f, q0=0.f, q1=0.f;
    for (int i = u; i < u + 502; ++i){
        float v0 = img[(i<<9) + c0], v1 = img[(i<<9) + c1];
        a0 += v0; q0 += v0*v0; a1 += v1; q1 += v1*v1;
    }
    __shared__ float cw[512], cw2[512];
    cw[c0] = a0; cw[c1] = a1; cw2[c0] = q0; cw2[c1] = q1;
    __shared__ double red[256], red2[256];
    red[threadIdx.x] = (double)a0 + (double)a1;
    red2[threadIdx.x] = (double)q0 + (double)q1;
    __syncthreads();
    for (int off = 128; off > 0; off >>= 1){
        if (threadIdx.x < off){ red[threadIdx.x] += red[threadIdx.x+off]; red2[threadIdx.x] += red2[threadIdx.x+off]; }
        __syncthreads();
    }
    if (threadIdx.x < 11){
        int v = threadIdx.x;
        double S1 = red[0], S2 = red2[0];
        for (int j = 0; j < v; ++j){ S1 -= (double)cw[j]; S2 -= (double)cw2[j]; }
        for (int j = v + 502; j < 512; ++j){ S1 -= (double)cw[j]; S2 -= (double)cw2[j]; }
        const double K = 502.0*502.0;
        double ivar = S2/K - (S1*S1)/(K*K*K) + 1e-8;
        if (ivar < 0.0) ivar = 0.0;
        den[b*121 + u*11 + v] = sqrt(stats[1] * ivar);
    }
}

// K2b: Nyquist-Nyquist coefficient  snn[b] = sum (-1)^(i+j) x
__global__ __launch_bounds__(256) void k_nyq(const float* __restrict__ fr, double* __restrict__ snn){
    int b = blockIdx.x;
    const float* img = fr + (size_t)b * NPIX;
    double s = 0.0;
    for (int idx = threadIdx.x; idx < NPIX; idx += 256){
        int i = idx >> 9, j = idx & 511;
        double v = (double)img[idx];
        s += ((i + j) & 1) ? -v : v;
    }
    __shared__ double rs[256];
    rs[threadIdx.x] = s; __syncthreads();
    for (int off = 128; off > 0; off >>= 1){
        if (threadIdx.x < off) rs[threadIdx.x] += rs[threadIdx.x+off];
        __syncthreads();
    }
    if (threadIdx.x == 0) snn[b] = rs[0];
}

// K3: direct shifted cross-correlation, 121 shifts, partial per (b, row-chunk)
__global__ __launch_bounds__(256, 1) void k_ncc(const float* __restrict__ fr, const float* __restrict__ tpl,
                                                const double* __restrict__ stats, float* __restrict__ partial){
    int b = blockIdx.x >> 3, chunk = blockIdx.x & 7;
    const float* img = fr + (size_t)b * NPIX;
    float mean = (float)stats[0];
    __shared__ float tr[16][544];          // ring of template rows, halo'd: tr[r%16][k] = t[r][(k-16)&511]-mean
    __shared__ float wred[4][121];
    int i0 = chunk * 64;
    for (int r = 0; r < 12; ++r){
        int row = (i0 - 5 + r + 512) & 511;
        float* dst2 = tr[row & 15];
        for (int k = threadIdx.x; k < 544; k += 256)
            dst2[k] = tpl[(row<<9) + ((k - 16) & 511)] - mean;
    }
    __syncthreads();
    float acc[11][11];
    #pragma unroll
    for (int a = 0; a < 11; ++a)
        #pragma unroll
        for (int c = 0; c < 11; ++c) acc[a][c] = 0.f;
    int j0 = (threadIdx.x & 127) << 2;     // 4 consecutive columns
    int half = threadIdx.x >> 7;           // row parity
    for (int k = 0; k < 32; ++k){
        int i = i0 + 2*k + half;
        float4 xv = *(const float4*)&img[(i<<9) + j0];
        float xm0 = xv.x, xm1 = xv.y, xm2 = xv.z, xm3 = xv.w;
        #pragma unroll
        for (int s0 = 0; s0 < 11; ++s0){
            int rowt = (i + 5 - s0 + 512) & 511;
            const float* trow = tr[rowt & 15];
            float tv[20];
            #pragma unroll
            for (int q = 0; q < 5; ++q)
                *(float4*)&tv[4*q] = *(const float4*)&trow[j0 + 8 + 4*q];   // t[(j0-8+q)&511]
            #pragma unroll
            for (int s1 = 0; s1 < 11; ++s1){
                acc[s0][s1] += xm0*tv[13-s1] + xm1*tv[14-s1] + xm2*tv[15-s1] + xm3*tv[16-s1];
            }
        }
        __syncthreads();
        if (k < 31){
            int r1 = (i0 + 2*k + 7) & 511, r2 = (i0 + 2*k + 8) & 511;
            float* d1 = tr[r1 & 15];
            float* d2 = tr[r2 & 15];
            for (int t = threadIdx.x; t < 1088; t += 256){
                int which = (t >= 544);
                int kk = which ? t - 544 : t;
                int row = which ? r2 : r1;
                float* d = which ? d2 : d1;
                d[kk] = tpl[(row<<9) + ((kk - 16) & 511)] - mean;
            }
        }
        __syncthreads();
    }
    int lane = threadIdx.x & 63, wv = threadIdx.x >> 6;
    #pragma unroll
    for (int e = 0; e < 121; ++e){
        float v = acc[e/11][e%11];
        v += __shfl_down(v, 32); v += __shfl_down(v, 16); v += __shfl_down(v, 8);
        v += __shfl_down(v, 4);  v += __shfl_down(v, 2);  v += __shfl_down(v, 1);
        if (lane == 0) wred[wv][e] = v;
    }
    __syncthreads();
    if (threadIdx.x < 121){
        int e = threadIdx.x;
        partial[(size_t)(b*8 + chunk)*121 + e] = wred[0][e] + wred[1][e] + wred[2][e] + wred[3][e];
    }
}

// K4: ncc, argmax, log-parabola subpixel -> shifts (double), c2 coefficient
__global__ __launch_bounds__(128) void k_shifts(const float* __restrict__ partial, const double* __restrict__ den,
                                                const double* __restrict__ snn, double* __restrict__ shx,
                                                double* __restrict__ shy, float* __restrict__ c2){
    int b = blockIdx.x;
    __shared__ double l[121], nc[121];
    for (int e = threadIdx.x; e < 121; e += 128){
        double s = 0.0;
        for (int c = 0; c < 8; ++c) s += (double)partial[(size_t)(b*8 + c)*121 + e];
        double nom = fabs(s);
        double v = nom / den[b*121 + e];
        if (v != v) v = 0.0;
        nc[e] = v;
        l[e] = log(v);
    }
    __syncthreads();
    if (threadIdx.x == 0){
        int am = 0; double best = nc[0];
        for (int e = 1; e < 121; ++e) if (nc[e] > best){ best = nc[e]; am = e; }
        int u = am / 11, v = am % 11;
        double sx = -(double)(u - 5), sy = -(double)(v - 5);
        int um1 = u - 1; if (um1 < 0) um1 += 11; if (um1 > 10) um1 = 10;
        int up1 = u + 1; if (up1 > 10) up1 = 10;
        int vm1 = v - 1; if (vm1 < 0) vm1 += 11; if (vm1 > 10) vm1 = 10;
        int vp1 = v + 1; if (vp1 > 10) vp1 = 10;
        double l0x4 = 4.0 * l[u*11 + v];
        double lm = l[um1*11 + v], lp = l[up1*11 + v];
        sx -= (lm - lp) / (2.0*lm - l0x4 + 2.0*lp);
        double lm2 = l[u*11 + vm1], lp2 = l[u*11 + vp1];
        sy -= (lm2 - lp2) / (2.0*lm2 - l0x4 + 2.0*lp2);
        shx[b] = sx; shy[b] = sy;
        double kx = sin(PI_D * sx) / 512.0, ky = sin(PI_D * sy) / 512.0;
        c2[b] = (float)(kx * ky * snn[b]);
    }
}

__device__ inline double grekern(int t, double s){
    double u = (double)t - s;
    if (u > 256.0) u -= 512.0;
    double a = PI_D * u / 512.0;
    double sp = sin(a);
    double D;
    if (fabs(sp) < 1e-12) D = cos(PI_D * u) / cos(a);     // u ~ 0
    else D = sin(PI_D * u) / (512.0 * sp);
    return D * cos(a);
}

// K4b: real parts of the Dirichlet shift kernels (imag part handled analytically via c2)
__global__ __launch_bounds__(256) void k_tables(const double* __restrict__ shx, const double* __restrict__ shy,
                                                float* __restrict__ ary, float* __restrict__ arx){
    int b = blockIdx.x;
    double sx = shx[b], sy = shy[b];
    for (int t = threadIdx.x; t < 512; t += 256){
        arx[(b<<9) + t] = (float)grekern(t, sx);
        ary[(b<<9) + t] = (float)grekern(t, sy);
    }
}

// K5/K6: out[r][p] = sum_m in[r][m] * kern[(p-m)&511]   (real circulant matmul), optional parity correction
template<int CORR>
__global__ __launch_bounds__(256) void k_rowcirc(const float* __restrict__ src, int src_local,
                                                 const float* __restrict__ kern_all,
                                                 float* __restrict__ dst,
                                                 const float* __restrict__ c2, int c0){
    int lb = blockIdx.x >> 5, blk = blockIdx.x & 31;
    int b = c0 + lb;
    const float* in = src + (size_t)(src_local ? lb : b) * NPIX;
    const float* kern = kern_all + ((size_t)b << 9);
    float* out = dst + (size_t)b * NPIX;
    __shared__ float kd[1024];
    __shared__ float Xr[16][512];
    int r0 = blk << 4;
    for (int idx = threadIdx.x; idx < 1024; idx += 256) kd[idx] = kern[idx & 511];
    for (int idx = threadIdx.x; idx < 8192; idx += 256){
        int rr = idx >> 9;
        Xr[rr][idx & 511] = in[((size_t)(r0 + rr) << 9) + (idx & 511)];
    }
    __syncthreads();
    int rg = threadIdx.x >> 6;
    int p0 = (threadIdx.x & 63) << 3;
    float acc[4][8];
    #pragma unroll
    for (int a = 0; a < 4; ++a)
        #pragma unroll
        for (int c = 0; c < 8; ++c) acc[a][c] = 0.f;
    for (int m = 0; m < 512; m += 4){
        int base = p0 - m + 508;                  // 4-aligned, in [0,1012]
        float4 kq0 = *(const float4*)&kd[base];
        float4 kq1 = *(const float4*)&kd[base + 4];
        float4 kq2 = *(const float4*)&kd[base + 8];
        float kw[12] = {kq0.x,kq0.y,kq0.z,kq0.w, kq1.x,kq1.y,kq1.z,kq1.w, kq2.x,kq2.y,kq2.z,kq2.w};
        #pragma unroll
        for (int rr = 0; rr < 4; ++rr){
            float4 xv = *(const float4*)&Xr[rg*4 + rr][m];
            float xm[4] = {xv.x, xv.y, xv.z, xv.w};
            #pragma unroll
            for (int mi = 0; mi < 4; ++mi)
                #pragma unroll
                for (int pp = 0; pp < 8; ++pp)
                    acc[rr][pp] += xm[mi] * kw[pp + 4 - mi];
        }
    }
    float cc = CORR ? c2[b] : 0.f;
    #pragma unroll
    for (int rr = 0; rr < 4; ++rr){
        int q = r0 + rg*4 + rr;
        float vals[8];
        #pragma unroll
        for (int pp = 0; pp < 8; ++pp){
            float v = acc[rr][pp];
            if (CORR){
                int p = p0 + pp;
                v -= ((q + p) & 1) ? -cc : cc;    // out -= c2 * (-1)^(p+q)
            }
            vals[pp] = v;
        }
        float4 o0 = {vals[0], vals[1], vals[2], vals[3]};
        float4 o1 = {vals[4], vals[5], vals[6], vals[7]};
        *(float4*)&out[((size_t)q << 9) + p0] = o0;
        *(float4*)&out[((size_t)q << 9) + p0 + 4] = o1;
    }
}

// transpose 512x512 (YRe in d_out -> YT in ws)
__global__ __launch_bounds__(256) void k_transpose(const float* __restrict__ in, float* __restrict__ out, int c0){
    int lb = blockIdx.x >> 8, tb = blockIdx.x & 255;
    int b = c0 + lb;
    int tx = (tb & 15) << 5, ty = ((tb >> 4) & 15) << 5;
    const float* src = in + (size_t)b * NPIX;
    float* dst = out + (size_t)lb * NPIX;
    __shared__ float tile[32][33];
    int col = threadIdx.x & 31, rw = threadIdx.x >> 5;
    #pragma unroll
    for (int k = 0; k < 4; ++k){
        int ry = rw + k*8;
        tile[ry][col] = src[((size_t)(ty + ry) << 9) + tx + col];
    }
    __syncthreads();
    #pragma unroll
    for (int k = 0; k < 4; ++k){
        int ry = rw + k*8;
        dst[((size_t)(tx + ry) << 9) + ty + col] = tile[col][ry];
    }
}

extern "C" void kernel_launch(void* const* d_in, const int* in_sizes, int n_in,
                              void* d_out, int out_size, void* d_ws, size_t ws_size,
                              hipStream_t stream){
    (void)in_sizes; (void)n_in; (void)out_size;
    const float* fr  = (const float*)d_in[0];   // (1,32,512,512,1) f32
    const float* tpl = (const float*)d_in[1];   // (512,512) f32
    float* out = (float*)d_out;                 // (32, 512*512) f32
    char* ws = (char*)d_ws;

    double* stats = (double*)(ws + 0);
    double* den   = (double*)(ws + 64);
    double* snn   = (double*)(ws + 31744);
    double* shx   = (double*)(ws + 32000);
    double* shy   = (double*)(ws + 32256);
    float*  c2    = (float*) (ws + 32512);
    float*  part  = (float*) (ws + 32768);
    float*  ary   = (float*) (ws + 157696);
    float*  arx   = (float*) (ws + 223232);
    float*  yt    = (float*) (ws + 524288);

    long long ytcap = ((long long)ws_size - 524288) / ((long long)NPIX * 4);
    int cb = (int)ytcap; if (cb > 32) cb = 32; if (cb < 1) cb = 1;

    k_template_stats<<<1, 256, 0, stream>>>(tpl, stats);
    k_winsums<<<352, 256, 0, stream>>>(fr, stats, den);
    k_nyq<<<32, 256, 0, stream>>>(fr, snn);
    k_ncc<<<256, 256, 0, stream>>>(fr, tpl, stats, part);
    k_shifts<<<32, 128, 0, stream>>>(part, den, snn, shx, shy, c2);
    k_tables<<<32, 256, 0, stream>>>(shx, shy, ary, arx);

    for (int c0 = 0; c0 < 32; c0 += cb){
        int nb = (32 - c0 < cb) ? (32 - c0) : cb;
        // stage 1: YRe[m][q] = sum_n x[m][n] * gyRe[(q-n)&511]   (stored in d_out region of batch)
        k_rowcirc<0><<<nb*32, 256, 0, stream>>>(fr, 0, ary, out, (const float*)nullptr, c0);
        // transpose YRe -> YT
        k_transpose<<<nb*256, 256, 0, stream>>>(out, yt, c0);
        // stage 2: out[q*512+p] = sum_m YT[q][m] * gxRe[(p-m)&511]  - c2*(-1)^(p+q)
        k_rowcirc<1><<<nb*32, 256, 0, stream>>>(yt, 1, arx, out, c2, c0);
    }
}

// Round 2
// 557.660 us; speedup vs baseline: 1.9423x; 1.9423x over previous
//
#include <hip/hip_runtime.h>
#include <hip/hip_bf16.h>
#include <math.h>

#define NPIX 262144          // 512*512
#define PI_D 3.14159265358979323846264338327950288

// ---------------- ws layout (byte offsets) ----------------
// 0      : double stats[2]            (mean_t, template_var)
// 64     : double stats_part[64][2]
// 2048   : double den[32][121]
// 33280  : double snn_part[32][8]
// 35328  : double shx[32]
// 35584  : double shy[32]
// 35840  : float  c2[32]
// 36096  : float  partial[32][8][121]
// 160256 : float  ary[32][512]
// 225792 : float  arx[32][512]
// 524288 : float  yt[cb][512][512]

// K1a: template partial sums (64 blocks, float4 loads, double accum)
__global__ __launch_bounds__(256) void k_stats_part(const float* __restrict__ t, double* __restrict__ part){
    int base = blockIdx.x * 4096;
    double s = 0.0, s2 = 0.0;
    #pragma unroll
    for (int k = 0; k < 4; ++k){
        float4 v = *(const float4*)&t[base + k*1024 + threadIdx.x*4];
        s  += (double)v.x + (double)v.y + (double)v.z + (double)v.w;
        s2 += (double)v.x*v.x + (double)v.y*v.y + (double)v.z*v.z + (double)v.w*v.w;
    }
    __shared__ double rs[256], rs2[256];
    rs[threadIdx.x] = s; rs2[threadIdx.x] = s2; __syncthreads();
    for (int off = 128; off > 0; off >>= 1){
        if (threadIdx.x < off){ rs[threadIdx.x] += rs[threadIdx.x+off]; rs2[threadIdx.x] += rs2[threadIdx.x+off]; }
        __syncthreads();
    }
    if (threadIdx.x == 0){ part[blockIdx.x*2] = rs[0]; part[blockIdx.x*2+1] = rs2[0]; }
}

// K1b: finalize template stats
__global__ __launch_bounds__(64) void k_stats_final(const double* __restrict__ part, double* __restrict__ stats){
    double s = part[threadIdx.x*2], s2 = part[threadIdx.x*2+1];
    #pragma unroll
    for (int off = 32; off > 0; off >>= 1){
        s  += __shfl_down(s, off);
        s2 += __shfl_down(s2, off);
    }
    if (threadIdx.x == 0){
        stats[0] = s / (double)NPIX;
        stats[1] = s2 - s*s/(double)NPIX + 1e-8;
    }
}

// K2: 502x502 window sums -> denominator[b][u][v] (double)
__global__ __launch_bounds__(256) void k_winsums(const float* __restrict__ fr, const double* __restrict__ stats,
                                                 double* __restrict__ den){
    int b = blockIdx.x / 11, u = blockIdx.x % 11;
    const float* img = fr + (size_t)b * NPIX;
    int c0 = threadIdx.x, c1 = threadIdx.x + 256;
    float a0=0.f, a1=0.f, q0=0.f, q1=0.f;
    for (int i = u; i < u + 502; ++i){
        float v0 = img[(i<<9) + c0], v1 = img[(i<<9) + c1];
        a0 += v0; q0 += v0*v0; a1 += v1; q1 += v1*v1;
    }
    __shared__ float cw[512], cw2[512];
    cw[c0] = a0; cw[c1] = a1; cw2[c0] = q0; cw2[c1] = q1;
    __shared__ double red[256], red2[256];
    red[threadIdx.x] = (double)a0 + (double)a1;
    red2[threadIdx.x] = (double)q0 + (double)q1;
    __syncthreads();
    for (int off = 128; off > 0; off >>= 1){
        if (threadIdx.x < off){ red[threadIdx.x] += red[threadIdx.x+off]; red2[threadIdx.x] += red2[threadIdx.x+off]; }
        __syncthreads();
    }
    if (threadIdx.x < 11){
        int v = threadIdx.x;
        double S1 = red[0], S2 = red2[0];
        for (int j = 0; j < v; ++j){ S1 -= (double)cw[j]; S2 -= (double)cw2[j]; }
        for (int j = v + 502; j < 512; ++j){ S1 -= (double)cw[j]; S2 -= (double)cw2[j]; }
        const double K = 502.0*502.0;
        double ivar = S2/K - (S1*S1)/(K*K*K) + 1e-8;
        if (ivar < 0.0) ivar = 0.0;
        den[b*121 + u*11 + v] = sqrt(stats[1] * ivar);
    }
}

// K2b: Nyquist-Nyquist partials  snn_part[b][chunk] = sum (-1)^(i+j) x over 64-row chunk
__global__ __launch_bounds__(256) void k_nyq(const float* __restrict__ fr, double* __restrict__ snn_part){
    int b = blockIdx.x >> 3, chunk = blockIdx.x & 7;
    const float* img = fr + (size_t)b * NPIX + (size_t)chunk * 32768;
    double s = 0.0;
    // 32768 floats = 8192 float4s; 256 threads * 32 iters
    for (int k = 0; k < 32; ++k){
        int idx4 = k*256 + threadIdx.x;          // float4 index within chunk
        float4 v = *(const float4*)&img[idx4*4];
        int i = (chunk*64) + (idx4 >> 7);        // row
        int j0 = (idx4 & 127) << 2;              // col of v.x
        float alt = v.x - v.y + v.z - v.w;
        s += ((i + j0) & 1) ? -(double)alt : (double)alt;
    }
    __shared__ double rs[256];
    rs[threadIdx.x] = s; __syncthreads();
    for (int off = 128; off > 0; off >>= 1){
        if (threadIdx.x < off) rs[threadIdx.x] += rs[threadIdx.x+off];
        __syncthreads();
    }
    if (threadIdx.x == 0) snn_part[b*8 + chunk] = rs[0];
}

// K3: direct shifted cross-correlation, 121 shifts, partial per (b, row-chunk)
__global__ __launch_bounds__(256, 1) void k_ncc(const float* __restrict__ fr, const float* __restrict__ tpl,
                                                const double* __restrict__ stats, float* __restrict__ partial){
    int b = blockIdx.x >> 3, chunk = blockIdx.x & 7;
    const float* img = fr + (size_t)b * NPIX;
    float mean = (float)stats[0];
    __shared__ float tr[16][544];          // ring of template rows, halo'd: tr[r%16][k] = t[r][(k-16)&511]-mean
    __shared__ float wred[4][121];
    int i0 = chunk * 64;
    for (int r = 0; r < 12; ++r){
        int row = (i0 - 5 + r + 512) & 511;
        float* dst2 = tr[row & 15];
        for (int k = threadIdx.x; k < 544; k += 256)
            dst2[k] = tpl[(row<<9) + ((k - 16) & 511)] - mean;
    }
    __syncthreads();
    float acc[11][11];
    #pragma unroll
    for (int a = 0; a < 11; ++a)
        #pragma unroll
        for (int c = 0; c < 11; ++c) acc[a][c] = 0.f;
    int j0 = (threadIdx.x & 127) << 2;     // 4 consecutive columns
    int half = threadIdx.x >> 7;           // row parity
    for (int k = 0; k < 32; ++k){
        int i = i0 + 2*k + half;
        float4 xv = *(const float4*)&img[(i<<9) + j0];
        float xm0 = xv.x, xm1 = xv.y, xm2 = xv.z, xm3 = xv.w;
        #pragma unroll
        for (int s0 = 0; s0 < 11; ++s0){
            int rowt = (i + 5 - s0 + 512) & 511;
            const float* trow = tr[rowt & 15];
            float tv[20];
            #pragma unroll
            for (int q = 0; q < 5; ++q)
                *(float4*)&tv[4*q] = *(const float4*)&trow[j0 + 8 + 4*q];   // t[(j0-8+q)&511]
            #pragma unroll
            for (int s1 = 0; s1 < 11; ++s1){
                acc[s0][s1] += xm0*tv[13-s1] + xm1*tv[14-s1] + xm2*tv[15-s1] + xm3*tv[16-s1];
            }
        }
        __syncthreads();
        if (k < 31){
            int r1 = (i0 + 2*k + 7) & 511, r2 = (i0 + 2*k + 8) & 511;
            float* d1 = tr[r1 & 15];
            float* d2 = tr[r2 & 15];
            for (int t = threadIdx.x; t < 1088; t += 256){
                int which = (t >= 544);
                int kk = which ? t - 544 : t;
                int row = which ? r2 : r1;
                float* d = which ? d2 : d1;
                d[kk] = tpl[(row<<9) + ((kk - 16) & 511)] - mean;
            }
        }
        __syncthreads();
    }
    int lane = threadIdx.x & 63, wv = threadIdx.x >> 6;
    #pragma unroll
    for (int e = 0; e < 121; ++e){
        float v = acc[e/11][e%11];
        v += __shfl_down(v, 32); v += __shfl_down(v, 16); v += __shfl_down(v, 8);
        v += __shfl_down(v, 4);  v += __shfl_down(v, 2);  v += __shfl_down(v, 1);
        if (lane == 0) wred[wv][e] = v;
    }
    __syncthreads();
    if (threadIdx.x < 121){
        int e = threadIdx.x;
        partial[(size_t)(b*8 + chunk)*121 + e] = wred[0][e] + wred[1][e] + wred[2][e] + wred[3][e];
    }
}

// K4: ncc, argmax, log-parabola subpixel -> shifts (double), c2 coefficient
__global__ __launch_bounds__(128) void k_shifts(const float* __restrict__ partial, const double* __restrict__ den,
                                                const double* __restrict__ snn_part, double* __restrict__ shx,
                                                double* __restrict__ shy, float* __restrict__ c2){
    int b = blockIdx.x;
    __shared__ double l[121], nc[121];
    for (int e = threadIdx.x; e < 121; e += 128){
        double s = 0.0;
        for (int c = 0; c < 8; ++c) s += (double)partial[(size_t)(b*8 + c)*121 + e];
        double nom = fabs(s);
        double v = nom / den[b*121 + e];
        if (v != v) v = 0.0;
        nc[e] = v;
        l[e] = log(v);
    }
    __syncthreads();
    if (threadIdx.x == 0){
        int am = 0; double best = nc[0];
        for (int e = 1; e < 121; ++e) if (nc[e] > best){ best = nc[e]; am = e; }
        int u = am / 11, v = am % 11;
        double sx = -(double)(u - 5), sy = -(double)(v - 5);
        int um1 = u - 1; if (um1 < 0) um1 += 11; if (um1 > 10) um1 = 10;
        int up1 = u + 1; if (up1 > 10) up1 = 10;
        int vm1 = v - 1; if (vm1 < 0) vm1 += 11; if (vm1 > 10) vm1 = 10;
        int vp1 = v + 1; if (vp1 > 10) vp1 = 10;
        double l0x4 = 4.0 * l[u*11 + v];
        double lm = l[um1*11 + v], lp = l[up1*11 + v];
        sx -= (lm - lp) / (2.0*lm - l0x4 + 2.0*lp);
        double lm2 = l[u*11 + vm1], lp2 = l[u*11 + vp1];
        sy -= (lm2 - lp2) / (2.0*lm2 - l0x4 + 2.0*lp2);
        shx[b] = sx; shy[b] = sy;
        double snn = 0.0;
        for (int c = 0; c < 8; ++c) snn += snn_part[b*8 + c];
        double kx = sin(PI_D * sx) / 512.0, ky = sin(PI_D * sy) / 512.0;
        c2[b] = (float)(kx * ky * snn);
    }
}

__device__ inline double grekern(int t, double s){
    double u = (double)t - s;
    if (u > 256.0) u -= 512.0;
    double a = PI_D * u / 512.0;
    double sp = sin(a);
    double D;
    if (fabs(sp) < 1e-12) D = cos(PI_D * u) / cos(a);     // u ~ 0
    else D = sin(PI_D * u) / (512.0 * sp);
    return D * cos(a);
}

// K4b: real parts of the Dirichlet shift kernels (imag part handled analytically via c2)
__global__ __launch_bounds__(256) void k_tables(const double* __restrict__ shx, const double* __restrict__ shy,
                                                float* __restrict__ ary, float* __restrict__ arx){
    int b = blockIdx.x;
    double sx = shx[b], sy = shy[b];
    for (int t = threadIdx.x; t < 512; t += 256){
        arx[(b<<9) + t] = (float)grekern(t, sx);
        ary[(b<<9) + t] = (float)grekern(t, sy);
    }
}

// K5/K6: out[r][p] = sum_m in[r][m] * kern[(p-m)&511]   (real circulant matmul), optional parity correction
template<int CORR>
__global__ __launch_bounds__(256) void k_rowcirc(const float* __restrict__ src, int src_local,
                                                 const float* __restrict__ kern_all,
                                                 float* __restrict__ dst,
                                                 const float* __restrict__ c2, int c0){
    int lb = blockIdx.x >> 5, blk = blockIdx.x & 31;
    int b = c0 + lb;
    const float* in = src + (size_t)(src_local ? lb : b) * NPIX;
    const float* kern = kern_all + ((size_t)b << 9);
    float* out = dst + (size_t)b * NPIX;
    __shared__ float kd[1024];
    __shared__ float Xr[16][512];
    int r0 = blk << 4;
    for (int idx = threadIdx.x; idx < 1024; idx += 256) kd[idx] = kern[idx & 511];
    for (int idx = threadIdx.x; idx < 8192; idx += 256){
        int rr = idx >> 9;
        Xr[rr][idx & 511] = in[((size_t)(r0 + rr) << 9) + (idx & 511)];
    }
    __syncthreads();
    int rg = threadIdx.x >> 6;
    int p0 = (threadIdx.x & 63) << 3;
    float acc[4][8];
    #pragma unroll
    for (int a = 0; a < 4; ++a)
        #pragma unroll
        for (int c = 0; c < 8; ++c) acc[a][c] = 0.f;
    for (int m = 0; m < 512; m += 4){
        int base = p0 - m + 508;                  // 4-aligned, in [0,1012]
        float4 kq0 = *(const float4*)&kd[base];
        float4 kq1 = *(const float4*)&kd[base + 4];
        float4 kq2 = *(const float4*)&kd[base + 8];
        float kw[12] = {kq0.x,kq0.y,kq0.z,kq0.w, kq1.x,kq1.y,kq1.z,kq1.w, kq2.x,kq2.y,kq2.z,kq2.w};
        #pragma unroll
        for (int rr = 0; rr < 4; ++rr){
            float4 xv = *(const float4*)&Xr[rg*4 + rr][m];
            float xm[4] = {xv.x, xv.y, xv.z, xv.w};
            #pragma unroll
            for (int mi = 0; mi < 4; ++mi)
                #pragma unroll
                for (int pp = 0; pp < 8; ++pp)
                    acc[rr][pp] += xm[mi] * kw[pp + 4 - mi];
        }
    }
    float cc = CORR ? c2[b] : 0.f;
    #pragma unroll
    for (int rr = 0; rr < 4; ++rr){
        int q = r0 + rg*4 + rr;
        float vals[8];
        #pragma unroll
        for (int pp = 0; pp < 8; ++pp){
            float v = acc[rr][pp];
            if (CORR){
                int p = p0 + pp;
                v -= ((q + p) & 1) ? -cc : cc;    // out -= c2 * (-1)^(p+q)
            }
            vals[pp] = v;
        }
        float4 o0 = {vals[0], vals[1], vals[2], vals[3]};
        float4 o1 = {vals[4], vals[5], vals[6], vals[7]};
        *(float4*)&out[((size_t)q << 9) + p0] = o0;
        *(float4*)&out[((size_t)q << 9) + p0 + 4] = o1;
    }
}

// transpose 512x512 (YRe in d_out -> YT in ws)
__global__ __launch_bounds__(256) void k_transpose(const float* __restrict__ in, float* __restrict__ out, int c0){
    int lb = blockIdx.x >> 8, tb = blockIdx.x & 255;
    int b = c0 + lb;
    int tx = (tb & 15) << 5, ty = ((tb >> 4) & 15) << 5;
    const float* src = in + (size_t)b * NPIX;
    float* dst = out + (size_t)lb * NPIX;
    __shared__ float tile[32][33];
    int col = threadIdx.x & 31, rw = threadIdx.x >> 5;
    #pragma unroll
    for (int k = 0; k < 4; ++k){
        int ry = rw + k*8;
        tile[ry][col] = src[((size_t)(ty + ry) << 9) + tx + col];
    }
    __syncthreads();
    #pragma unroll
    for (int k = 0; k < 4; ++k){
        int ry = rw + k*8;
        dst[((size_t)(tx + ry) << 9) + ty + col] = tile[col][ry];
    }
}

extern "C" void kernel_launch(void* const* d_in, const int* in_sizes, int n_in,
                              void* d_out, int out_size, void* d_ws, size_t ws_size,
                              hipStream_t stream){
    (void)in_sizes; (void)n_in; (void)out_size;
    const float* fr  = (const float*)d_in[0];   // (1,32,512,512,1) f32
    const float* tpl = (const float*)d_in[1];   // (512,512) f32
    float* out = (float*)d_out;                 // (32, 512*512) f32
    char* ws = (char*)d_ws;

    double* stats  = (double*)(ws + 0);
    double* spart  = (double*)(ws + 64);
    double* den    = (double*)(ws + 2048);
    double* snnp   = (double*)(ws + 33280);
    double* shx    = (double*)(ws + 35328);
    double* shy    = (double*)(ws + 35584);
    float*  c2     = (float*) (ws + 35840);
    float*  part   = (float*) (ws + 36096);
    float*  ary    = (float*) (ws + 160256);
    float*  arx    = (float*) (ws + 225792);
    float*  yt     = (float*) (ws + 524288);

    long long ytcap = ((long long)ws_size - 524288) / ((long long)NPIX * 4);
    int cb = (int)ytcap; if (cb > 32) cb = 32; if (cb < 1) cb = 1;

    k_stats_part<<<64, 256, 0, stream>>>(tpl, spart);
    k_stats_final<<<1, 64, 0, stream>>>(spart, stats);
    k_winsums<<<352, 256, 0, stream>>>(fr, stats, den);
    k_nyq<<<256, 256, 0, stream>>>(fr, snnp);
    k_ncc<<<256, 256, 0, stream>>>(fr, tpl, stats, part);
    k_shifts<<<32, 128, 0, stream>>>(part, den, snnp, shx, shy, c2);
    k_tables<<<32, 256, 0, stream>>>(shx, shy, ary, arx);

    for (int c0 = 0; c0 < 32; c0 += cb){
        int nb = (32 - c0 < cb) ? (32 - c0) : cb;
        // stage 1: YRe[m][q] = sum_n x[m][n] * gyRe[(q-n)&511]   (stored in d_out region of batch)
        k_rowcirc<0><<<nb*32, 256, 0, stream>>>(fr, 0, ary, out, (const float*)nullptr, c0);
        // transpose YRe -> YT
        k_transpose<<<nb*256, 256, 0, stream>>>(out, yt, c0);
        // stage 2: out[q*512+p] = sum_m YT[q][m] * gxRe[(p-m)&511]  - c2*(-1)^(p+q)
        k_rowcirc<1><<<nb*32, 256, 0, stream>>>(yt, 1, arx, out, c2, c0);
    }
}

// Round 3
// 450.838 us; speedup vs baseline: 2.4026x; 1.2369x over previous
//
#include <hip/hip_runtime.h>
#include <hip/hip_bf16.h>
#include <math.h>

#define NPIX 262144          // 512*512
#define PI_D 3.14159265358979323846264338327950288

// ---------------- ws layout (byte offsets) ----------------
// 0       : double stats[2]            (mean_t, template_var)
// 64      : double spart[64][2]
// 2048    : double den[32][121]
// 33280   : double snn_part[32][8]
// 35328   : double shx[32]
// 35584   : double shy[32]
// 35840   : float  c2[32]
// 36096   : float  partial[32][8][121]
// 160256  : float  ary[32][512]
// 225792  : float  arx[32][512]
// 294912  : float  csum[32][8][512]
// 819200  : float  csum2[32][8][512]
// 1572864 : float  yt[cb][512][512]

// K1a: template partial sums (64 blocks, float4 loads, double accum)
__global__ __launch_bounds__(256) void k_stats_part(const float* __restrict__ t, double* __restrict__ part){
    int base = blockIdx.x * 4096;
    double s = 0.0, s2 = 0.0;
    #pragma unroll
    for (int k = 0; k < 4; ++k){
        float4 v = *(const float4*)&t[base + k*1024 + threadIdx.x*4];
        s  += (double)v.x + (double)v.y + (double)v.z + (double)v.w;
        s2 += (double)v.x*v.x + (double)v.y*v.y + (double)v.z*v.z + (double)v.w*v.w;
    }
    __shared__ double rs[256], rs2[256];
    rs[threadIdx.x] = s; rs2[threadIdx.x] = s2; __syncthreads();
    for (int off = 128; off > 0; off >>= 1){
        if (threadIdx.x < off){ rs[threadIdx.x] += rs[threadIdx.x+off]; rs2[threadIdx.x] += rs2[threadIdx.x+off]; }
        __syncthreads();
    }
    if (threadIdx.x == 0){ part[blockIdx.x*2] = rs[0]; part[blockIdx.x*2+1] = rs2[0]; }
}

// K1b: finalize template stats
__global__ __launch_bounds__(64) void k_stats_final(const double* __restrict__ part, double* __restrict__ stats){
    double s = part[threadIdx.x*2], s2 = part[threadIdx.x*2+1];
    #pragma unroll
    for (int off = 32; off > 0; off >>= 1){
        s  += __shfl_down(s, off);
        s2 += __shfl_down(s2, off);
    }
    if (threadIdx.x == 0){
        stats[0] = s / (double)NPIX;
        stats[1] = s2 - s*s/(double)NPIX + 1e-8;
    }
}

// K2a: per-chunk column sums (+squares) over 64 rows, fused with Nyquist alternating sum
__global__ __launch_bounds__(256) void k_colsums(const float* __restrict__ fr, float* __restrict__ csum,
                                                 float* __restrict__ csum2, double* __restrict__ snn_part){
    int b = blockIdx.x >> 3, chunk = blockIdx.x & 7;
    const float* img = fr + (size_t)b * NPIX + (size_t)chunk * (64*512);
    int t = threadIdx.x;
    float a0=0.f, q0=0.f, a1=0.f, q1=0.f;
    double sn = 0.0;
    for (int r = 0; r < 64; ++r){
        float v0 = img[(r<<9) + t];
        float v1 = img[(r<<9) + t + 256];
        a0 += v0; q0 += v0*v0; a1 += v1; q1 += v1*v1;
        float sv = v0 + v1;                         // cols t and t+256 share parity
        sn += ((r + t) & 1) ? -(double)sv : (double)sv;   // (-1)^(row+col), chunk*64 even
    }
    size_t o = ((size_t)(b*8 + chunk) << 9) + t;
    csum[o] = a0;  csum[o + 256] = a1;
    csum2[o] = q0; csum2[o + 256] = q1;
    __shared__ double rs[256];
    rs[t] = sn; __syncthreads();
    for (int off = 128; off > 0; off >>= 1){
        if (t < off) rs[t] += rs[t+off];
        __syncthreads();
    }
    if (t == 0) snn_part[b*8 + chunk] = rs[0];
}

// K2b: finalize 121 window denominators per image from column sums + edges
__global__ __launch_bounds__(256) void k_winfin(const float* __restrict__ fr, const float* __restrict__ csum,
                                                const float* __restrict__ csum2, const double* __restrict__ stats,
                                                double* __restrict__ den){
    int b = blockIdx.x;
    const float* img = fr + (size_t)b * NPIX;
    __shared__ double fc[512], fc2[512];
    __shared__ double rsum[20], rsum2[20];
    __shared__ float E[20][20], E2[20][20];
    __shared__ double red[256], red2[256];
    int t = threadIdx.x;
    for (int c = t; c < 512; c += 256){
        double s = 0.0, s2 = 0.0;
        for (int k = 0; k < 8; ++k){
            size_t o = ((size_t)(b*8 + k) << 9) + c;
            s += (double)csum[o]; s2 += (double)csum2[o];
        }
        fc[c] = s; fc2[c] = s2;
    }
    if (t < 400){
        int i = t / 20, j = t % 20;
        int row = (i < 10) ? i : (i + 492);    // rows 0..9, 502..511
        int col = (j < 10) ? j : (j + 492);
        float v = img[(row<<9) + col];
        E[i][j] = v; E2[i][j] = v*v;
    }
    __syncthreads();
    red[t] = fc[t] + fc[t+256];
    red2[t] = fc2[t] + fc2[t+256];
    __syncthreads();
    for (int off = 128; off > 0; off >>= 1){
        if (t < off){ red[t] += red[t+off]; red2[t] += red2[t+off]; }
        __syncthreads();
    }
    double F1 = red[0], F2 = red2[0];
    int lane = t & 63, wv = t >> 6;
    for (int e = wv; e < 20; e += 4){
        int row = (e < 10) ? e : (e + 492);
        double s = 0.0, s2 = 0.0;
        for (int c = lane; c < 512; c += 64){
            float v = img[(row<<9) + c];
            s += v; s2 += (double)v*v;
        }
        #pragma unroll
        for (int off = 32; off > 0; off >>= 1){ s += __shfl_down(s, off); s2 += __shfl_down(s2, off); }
        if (lane == 0){ rsum[e] = s; rsum2[e] = s2; }
    }
    __syncthreads();
    if (t < 121){
        int u = t / 11, v = t % 11;
        double S1 = F1, S2 = F2;
        for (int i = 0; i < u; ++i){ S1 -= rsum[i]; S2 -= rsum2[i]; }          // excluded top rows 0..u-1
        for (int k = 10+u; k < 20; ++k){ S1 -= rsum[k]; S2 -= rsum2[k]; }      // excluded bottom rows u+502..511
        for (int j = 0; j < v; ++j){                                           // excluded left cols, minus corners
            double cw = fc[j], cq = fc2[j];
            for (int i = 0; i < u; ++i){ cw -= E[i][j]; cq -= E2[i][j]; }
            for (int k = 10+u; k < 20; ++k){ cw -= E[k][j]; cq -= E2[k][j]; }
            S1 -= cw; S2 -= cq;
        }
        for (int jj = 10+v; jj < 20; ++jj){                                    // excluded right cols v+502..511
            int col = jj + 492;
            double cw = fc[col], cq = fc2[col];
            for (int i = 0; i < u; ++i){ cw -= E[i][jj]; cq -= E2[i][jj]; }
            for (int k = 10+u; k < 20; ++k){ cw -= E[k][jj]; cq -= E2[k][jj]; }
            S1 -= cw; S2 -= cq;
        }
        const double K = 502.0*502.0;
        double ivar = S2/K - (S1*S1)/(K*K*K) + 1e-8;
        if (ivar < 0.0) ivar = 0.0;
        den[b*121 + u*11 + v] = sqrt(stats[1] * ivar);
    }
}

// K3: direct shifted cross-correlation, 121 shifts, partial per (b, row-chunk)
__global__ __launch_bounds__(256, 1) void k_ncc(const float* __restrict__ fr, const float* __restrict__ tpl,
                                                const double* __restrict__ stats, float* __restrict__ partial){
    int b = blockIdx.x >> 3, chunk = blockIdx.x & 7;
    const float* img = fr + (size_t)b * NPIX;
    float mean = (float)stats[0];
    __shared__ float tr[16][544];          // ring of template rows, halo'd: tr[r%16][k] = t[r][(k-16)&511]-mean
    __shared__ float wred[4][121];
    int i0 = chunk * 64;
    for (int r = 0; r < 12; ++r){
        int row = (i0 - 5 + r + 512) & 511;
        float* dst2 = tr[row & 15];
        for (int k = threadIdx.x; k < 544; k += 256)
            dst2[k] = tpl[(row<<9) + ((k - 16) & 511)] - mean;
    }
    __syncthreads();
    float acc[11][11];
    #pragma unroll
    for (int a = 0; a < 11; ++a)
        #pragma unroll
        for (int c = 0; c < 11; ++c) acc[a][c] = 0.f;
    int j0 = (threadIdx.x & 127) << 2;     // 4 consecutive columns
    int half = threadIdx.x >> 7;           // row parity
    for (int k = 0; k < 32; ++k){
        int i = i0 + 2*k + half;
        float4 xv = *(const float4*)&img[(i<<9) + j0];
        float xm0 = xv.x, xm1 = xv.y, xm2 = xv.z, xm3 = xv.w;
        #pragma unroll
        for (int s0 = 0; s0 < 11; ++s0){
            int rowt = (i + 5 - s0 + 512) & 511;
            const float* trow = tr[rowt & 15];
            float tv[20];
            #pragma unroll
            for (int q = 0; q < 5; ++q)
                *(float4*)&tv[4*q] = *(const float4*)&trow[j0 + 8 + 4*q];   // t[(j0-8+q)&511]
            #pragma unroll
            for (int s1 = 0; s1 < 11; ++s1){
                acc[s0][s1] += xm0*tv[13-s1] + xm1*tv[14-s1] + xm2*tv[15-s1] + xm3*tv[16-s1];
            }
        }
        __syncthreads();
        if (k < 31){
            int r1 = (i0 + 2*k + 7) & 511, r2 = (i0 + 2*k + 8) & 511;
            float* d1 = tr[r1 & 15];
            float* d2 = tr[r2 & 15];
            for (int t = threadIdx.x; t < 1088; t += 256){
                int which = (t >= 544);
                int kk = which ? t - 544 : t;
                int row = which ? r2 : r1;
                float* d = which ? d2 : d1;
                d[kk] = tpl[(row<<9) + ((kk - 16) & 511)] - mean;
            }
        }
        __syncthreads();
    }
    int lane = threadIdx.x & 63, wv = threadIdx.x >> 6;
    #pragma unroll
    for (int e = 0; e < 121; ++e){
        float v = acc[e/11][e%11];
        v += __shfl_down(v, 32); v += __shfl_down(v, 16); v += __shfl_down(v, 8);
        v += __shfl_down(v, 4);  v += __shfl_down(v, 2);  v += __shfl_down(v, 1);
        if (lane == 0) wred[wv][e] = v;
    }
    __syncthreads();
    if (threadIdx.x < 121){
        int e = threadIdx.x;
        partial[(size_t)(b*8 + chunk)*121 + e] = wred[0][e] + wred[1][e] + wred[2][e] + wred[3][e];
    }
}

// K4: ncc, argmax, log-parabola subpixel -> shifts (double), c2 coefficient
__global__ __launch_bounds__(128) void k_shifts(const float* __restrict__ partial, const double* __restrict__ den,
                                                const double* __restrict__ snn_part, double* __restrict__ shx,
                                                double* __restrict__ shy, float* __restrict__ c2){
    int b = blockIdx.x;
    __shared__ double l[121], nc[121];
    for (int e = threadIdx.x; e < 121; e += 128){
        double s = 0.0;
        for (int c = 0; c < 8; ++c) s += (double)partial[(size_t)(b*8 + c)*121 + e];
        double nom = fabs(s);
        double v = nom / den[b*121 + e];
        if (v != v) v = 0.0;
        nc[e] = v;
        l[e] = log(v);
    }
    __syncthreads();
    if (threadIdx.x == 0){
        int am = 0; double best = nc[0];
        for (int e = 1; e < 121; ++e) if (nc[e] > best){ best = nc[e]; am = e; }
        int u = am / 11, v = am % 11;
        double sx = -(double)(u - 5), sy = -(double)(v - 5);
        int um1 = u - 1; if (um1 < 0) um1 += 11; if (um1 > 10) um1 = 10;
        int up1 = u + 1; if (up1 > 10) up1 = 10;
        int vm1 = v - 1; if (vm1 < 0) vm1 += 11; if (vm1 > 10) vm1 = 10;
        int vp1 = v + 1; if (vp1 > 10) vp1 = 10;
        double l0x4 = 4.0 * l[u*11 + v];
        double lm = l[um1*11 + v], lp = l[up1*11 + v];
        sx -= (lm - lp) / (2.0*lm - l0x4 + 2.0*lp);
        double lm2 = l[u*11 + vm1], lp2 = l[u*11 + vp1];
        sy -= (lm2 - lp2) / (2.0*lm2 - l0x4 + 2.0*lp2);
        shx[b] = sx; shy[b] = sy;
        double snn = 0.0;
        for (int c = 0; c < 8; ++c) snn += snn_part[b*8 + c];
        double kx = sin(PI_D * sx) / 512.0, ky = sin(PI_D * sy) / 512.0;
        c2[b] = (float)(kx * ky * snn);
    }
}

__device__ inline double grekern(int t, double s){
    double u = (double)t - s;
    if (u > 256.0) u -= 512.0;
    double a = PI_D * u / 512.0;
    double sp = sin(a);
    double D;
    if (fabs(sp) < 1e-12) D = cos(PI_D * u) / cos(a);     // u ~ 0
    else D = sin(PI_D * u) / (512.0 * sp);
    return D * cos(a);
}

// K4b: real parts of the Dirichlet shift kernels (imag part handled analytically via c2)
__global__ __launch_bounds__(256) void k_tables(const double* __restrict__ shx, const double* __restrict__ shy,
                                                float* __restrict__ ary, float* __restrict__ arx){
    int b = blockIdx.x;
    double sx = shx[b], sy = shy[b];
    for (int t = threadIdx.x; t < 512; t += 256){
        arx[(b<<9) + t] = (float)grekern(t, sx);
        ary[(b<<9) + t] = (float)grekern(t, sy);
    }
}

// K5/K6: out[r][p] = sum_m in[r][m] * kern[(p-m)&511]   (real circulant matmul), optional parity correction
template<int CORR>
__global__ __launch_bounds__(256) void k_rowcirc(const float* __restrict__ src, int src_local,
                                                 const float* __restrict__ kern_all,
                                                 float* __restrict__ dst,
                                                 const float* __restrict__ c2, int c0){
    int lb = blockIdx.x >> 5, blk = blockIdx.x & 31;
    int b = c0 + lb;
    const float* in = src + (size_t)(src_local ? lb : b) * NPIX;
    const float* kern = kern_all + ((size_t)b << 9);
    float* out = dst + (size_t)b * NPIX;
    __shared__ float kd[1024];
    __shared__ float Xr[16][512];
    int r0 = blk << 4;
    for (int idx = threadIdx.x; idx < 1024; idx += 256) kd[idx] = kern[idx & 511];
    for (int idx = threadIdx.x; idx < 8192; idx += 256){
        int rr = idx >> 9;
        Xr[rr][idx & 511] = in[((size_t)(r0 + rr) << 9) + (idx & 511)];
    }
    __syncthreads();
    int rg = threadIdx.x >> 6;
    int p0 = (threadIdx.x & 63) << 3;
    float acc[4][8];
    #pragma unroll
    for (int a = 0; a < 4; ++a)
        #pragma unroll
        for (int c = 0; c < 8; ++c) acc[a][c] = 0.f;
    for (int m = 0; m < 512; m += 4){
        int base = p0 - m + 508;                  // 4-aligned, in [0,1012]
        float4 kq0 = *(const float4*)&kd[base];
        float4 kq1 = *(const float4*)&kd[base + 4];
        float4 kq2 = *(const float4*)&kd[base + 8];
        float kw[12] = {kq0.x,kq0.y,kq0.z,kq0.w, kq1.x,kq1.y,kq1.z,kq1.w, kq2.x,kq2.y,kq2.z,kq2.w};
        #pragma unroll
        for (int rr = 0; rr < 4; ++rr){
            float4 xv = *(const float4*)&Xr[rg*4 + rr][m];
            float xm[4] = {xv.x, xv.y, xv.z, xv.w};
            #pragma unroll
            for (int mi = 0; mi < 4; ++mi)
                #pragma unroll
                for (int pp = 0; pp < 8; ++pp)
                    acc[rr][pp] += xm[mi] * kw[pp + 4 - mi];
        }
    }
    float cc = CORR ? c2[b] : 0.f;
    #pragma unroll
    for (int rr = 0; rr < 4; ++rr){
        int q = r0 + rg*4 + rr;
        float vals[8];
        #pragma unroll
        for (int pp = 0; pp < 8; ++pp){
            float v = acc[rr][pp];
            if (CORR){
                int p = p0 + pp;
                v -= ((q + p) & 1) ? -cc : cc;    // out -= c2 * (-1)^(p+q)
            }
            vals[pp] = v;
        }
        float4 o0 = {vals[0], vals[1], vals[2], vals[3]};
        float4 o1 = {vals[4], vals[5], vals[6], vals[7]};
        *(float4*)&out[((size_t)q << 9) + p0] = o0;
        *(float4*)&out[((size_t)q << 9) + p0 + 4] = o1;
    }
}

// transpose 512x512 (YRe in d_out -> YT in ws)
__global__ __launch_bounds__(256) void k_transpose(const float* __restrict__ in, float* __restrict__ out, int c0){
    int lb = blockIdx.x >> 8, tb = blockIdx.x & 255;
    int b = c0 + lb;
    int tx = (tb & 15) << 5, ty = ((tb >> 4) & 15) << 5;
    const float* src = in + (size_t)b * NPIX;
    float* dst = out + (size_t)lb * NPIX;
    __shared__ float tile[32][33];
    int col = threadIdx.x & 31, rw = threadIdx.x >> 5;
    #pragma unroll
    for (int k = 0; k < 4; ++k){
        int ry = rw + k*8;
        tile[ry][col] = src[((size_t)(ty + ry) << 9) + tx + col];
    }
    __syncthreads();
    #pragma unroll
    for (int k = 0; k < 4; ++k){
        int ry = rw + k*8;
        dst[((size_t)(tx + ry) << 9) + ty + col] = tile[col][ry];
    }
}

extern "C" void kernel_launch(void* const* d_in, const int* in_sizes, int n_in,
                              void* d_out, int out_size, void* d_ws, size_t ws_size,
                              hipStream_t stream){
    (void)in_sizes; (void)n_in; (void)out_size;
    const float* fr  = (const float*)d_in[0];   // (1,32,512,512,1) f32
    const float* tpl = (const float*)d_in[1];   // (512,512) f32
    float* out = (float*)d_out;                 // (32, 512*512) f32
    char* ws = (char*)d_ws;

    double* stats  = (double*)(ws + 0);
    double* spart  = (double*)(ws + 64);
    double* den    = (double*)(ws + 2048);
    double* snnp   = (double*)(ws + 33280);
    double* shx    = (double*)(ws + 35328);
    double* shy    = (double*)(ws + 35584);
    float*  c2     = (float*) (ws + 35840);
    float*  part   = (float*) (ws + 36096);
    float*  ary    = (float*) (ws + 160256);
    float*  arx    = (float*) (ws + 225792);
    float*  csum   = (float*) (ws + 294912);
    float*  csum2  = (float*) (ws + 819200);
    float*  yt     = (float*) (ws + 1572864);

    long long ytcap = ((long long)ws_size - 1572864) / ((long long)NPIX * 4);
    int cb = (int)ytcap; if (cb > 32) cb = 32; if (cb < 1) cb = 1;

    k_stats_part<<<64, 256, 0, stream>>>(tpl, spart);
    k_stats_final<<<1, 64, 0, stream>>>(spart, stats);
    k_colsums<<<256, 256, 0, stream>>>(fr, csum, csum2, snnp);
    k_winfin<<<32, 256, 0, stream>>>(fr, csum, csum2, stats, den);
    k_ncc<<<256, 256, 0, stream>>>(fr, tpl, stats, part);
    k_shifts<<<32, 128, 0, stream>>>(part, den, snnp, shx, shy, c2);
    k_tables<<<32, 256, 0, stream>>>(shx, shy, ary, arx);

    for (int c0 = 0; c0 < 32; c0 += cb){
        int nb = (32 - c0 < cb) ? (32 - c0) : cb;
        // stage 1: YRe[m][q] = sum_n x[m][n] * gyRe[(q-n)&511]   (stored in d_out region of batch)
        k_rowcirc<0><<<nb*32, 256, 0, stream>>>(fr, 0, ary, out, (const float*)nullptr, c0);
        // transpose YRe -> YT
        k_transpose<<<nb*256, 256, 0, stream>>>(out, yt, c0);
        // stage 2: out[q*512+p] = sum_m YT[q][m] * gxRe[(p-m)&511]  - c2*(-1)^(p+q)
        k_rowcirc<1><<<nb*32, 256, 0, stream>>>(yt, 1, arx, out, c2, c0);
    }
}

// Round 4
// 425.322 us; speedup vs baseline: 2.5467x; 1.0600x over previous
//
#include <hip/hip_runtime.h>
#include <hip/hip_bf16.h>
#include <math.h>

#define NPIX 262144          // 512*512
#define PI_D 3.14159265358979323846264338327950288

// ---------------- ws layout (byte offsets) ----------------
// 0       : double stats[2]            (mean_t, template_var)
// 64      : double spart[64][2]
// 2048    : double den[32][121]
// 33280   : double snn_part[32][8]
// 35328   : double shx[32]
// 35584   : double shy[32]
// 35840   : float  c2[32]
// 36096   : float  partial[32][32][121]   (495,616 B)
// 532480  : float  ary[32][512]
// 598016  : float  arx[32][512]
// 663552  : float  csum[32][8][512]
// 1187840 : float  csum2[32][8][512]
// 2097152 : float  yt[cb][512][512]

// K1a: template partial sums (64 blocks, float4 loads, double accum)
__global__ __launch_bounds__(256) void k_stats_part(const float* __restrict__ t, double* __restrict__ part){
    int base = blockIdx.x * 4096;
    double s = 0.0, s2 = 0.0;
    #pragma unroll
    for (int k = 0; k < 4; ++k){
        float4 v = *(const float4*)&t[base + k*1024 + threadIdx.x*4];
        s  += (double)v.x + (double)v.y + (double)v.z + (double)v.w;
        s2 += (double)v.x*v.x + (double)v.y*v.y + (double)v.z*v.z + (double)v.w*v.w;
    }
    __shared__ double rs[256], rs2[256];
    rs[threadIdx.x] = s; rs2[threadIdx.x] = s2; __syncthreads();
    for (int off = 128; off > 0; off >>= 1){
        if (threadIdx.x < off){ rs[threadIdx.x] += rs[threadIdx.x+off]; rs2[threadIdx.x] += rs2[threadIdx.x+off]; }
        __syncthreads();
    }
    if (threadIdx.x == 0){ part[blockIdx.x*2] = rs[0]; part[blockIdx.x*2+1] = rs2[0]; }
}

// K1b: finalize template stats
__global__ __launch_bounds__(64) void k_stats_final(const double* __restrict__ part, double* __restrict__ stats){
    double s = part[threadIdx.x*2], s2 = part[threadIdx.x*2+1];
    #pragma unroll
    for (int off = 32; off > 0; off >>= 1){
        s  += __shfl_down(s, off);
        s2 += __shfl_down(s2, off);
    }
    if (threadIdx.x == 0){
        stats[0] = s / (double)NPIX;
        stats[1] = s2 - s*s/(double)NPIX + 1e-8;
    }
}

// K2a: per-chunk column sums (+squares) over 64 rows, fused with Nyquist alternating sum
__global__ __launch_bounds__(256) void k_colsums(const float* __restrict__ fr, float* __restrict__ csum,
                                                 float* __restrict__ csum2, double* __restrict__ snn_part){
    int b = blockIdx.x >> 3, chunk = blockIdx.x & 7;
    const float* img = fr + (size_t)b * NPIX + (size_t)chunk * (64*512);
    int t = threadIdx.x;
    float a0=0.f, q0=0.f, a1=0.f, q1=0.f;
    double sn = 0.0;
    for (int r = 0; r < 64; ++r){
        float v0 = img[(r<<9) + t];
        float v1 = img[(r<<9) + t + 256];
        a0 += v0; q0 += v0*v0; a1 += v1; q1 += v1*v1;
        float sv = v0 + v1;                         // cols t and t+256 share parity
        sn += ((r + t) & 1) ? -(double)sv : (double)sv;   // (-1)^(row+col), chunk*64 even
    }
    size_t o = ((size_t)(b*8 + chunk) << 9) + t;
    csum[o] = a0;  csum[o + 256] = a1;
    csum2[o] = q0; csum2[o + 256] = q1;
    __shared__ double rs[256];
    rs[t] = sn; __syncthreads();
    for (int off = 128; off > 0; off >>= 1){
        if (t < off) rs[t] += rs[t+off];
        __syncthreads();
    }
    if (t == 0) snn_part[b*8 + chunk] = rs[0];
}

// K2b: finalize 121 window denominators per image from column sums + edges
__global__ __launch_bounds__(256) void k_winfin(const float* __restrict__ fr, const float* __restrict__ csum,
                                                const float* __restrict__ csum2, const double* __restrict__ stats,
                                                double* __restrict__ den){
    int b = blockIdx.x;
    const float* img = fr + (size_t)b * NPIX;
    __shared__ double fc[512], fc2[512];
    __shared__ double rsum[20], rsum2[20];
    __shared__ float E[20][20], E2[20][20];
    __shared__ double red[256], red2[256];
    int t = threadIdx.x;
    for (int c = t; c < 512; c += 256){
        double s = 0.0, s2 = 0.0;
        for (int k = 0; k < 8; ++k){
            size_t o = ((size_t)(b*8 + k) << 9) + c;
            s += (double)csum[o]; s2 += (double)csum2[o];
        }
        fc[c] = s; fc2[c] = s2;
    }
    if (t < 400){
        int i = t / 20, j = t % 20;
        int row = (i < 10) ? i : (i + 492);    // rows 0..9, 502..511
        int col = (j < 10) ? j : (j + 492);
        float v = img[(row<<9) + col];
        E[i][j] = v; E2[i][j] = v*v;
    }
    __syncthreads();
    red[t] = fc[t] + fc[t+256];
    red2[t] = fc2[t] + fc2[t+256];
    __syncthreads();
    for (int off = 128; off > 0; off >>= 1){
        if (t < off){ red[t] += red[t+off]; red2[t] += red2[t+off]; }
        __syncthreads();
    }
    double F1 = red[0], F2 = red2[0];
    int lane = t & 63, wv = t >> 6;
    for (int e = wv; e < 20; e += 4){
        int row = (e < 10) ? e : (e + 492);
        double s = 0.0, s2 = 0.0;
        for (int c = lane; c < 512; c += 64){
            float v = img[(row<<9) + c];
            s += v; s2 += (double)v*v;
        }
        #pragma unroll
        for (int off = 32; off > 0; off >>= 1){ s += __shfl_down(s, off); s2 += __shfl_down(s2, off); }
        if (lane == 0){ rsum[e] = s; rsum2[e] = s2; }
    }
    __syncthreads();
    if (t < 121){
        int u = t / 11, v = t % 11;
        double S1 = F1, S2 = F2;
        for (int i = 0; i < u; ++i){ S1 -= rsum[i]; S2 -= rsum2[i]; }          // excluded top rows 0..u-1
        for (int k = 10+u; k < 20; ++k){ S1 -= rsum[k]; S2 -= rsum2[k]; }      // excluded bottom rows u+502..511
        for (int j = 0; j < v; ++j){                                           // excluded left cols, minus corners
            double cw = fc[j], cq = fc2[j];
            for (int i = 0; i < u; ++i){ cw -= E[i][j]; cq -= E2[i][j]; }
            for (int k = 10+u; k < 20; ++k){ cw -= E[k][j]; cq -= E2[k][j]; }
            S1 -= cw; S2 -= cq;
        }
        for (int jj = 10+v; jj < 20; ++jj){                                    // excluded right cols v+502..511
            int col = jj + 492;
            double cw = fc[col], cq = fc2[col];
            for (int i = 0; i < u; ++i){ cw -= E[i][jj]; cq -= E2[i][jj]; }
            for (int k = 10+u; k < 20; ++k){ cw -= E[k][jj]; cq -= E2[k][jj]; }
            S1 -= cw; S2 -= cq;
        }
        const double K = 502.0*502.0;
        double ivar = S2/K - (S1*S1)/(K*K*K) + 1e-8;
        if (ivar < 0.0) ivar = 0.0;
        den[b*121 + u*11 + v] = sqrt(stats[1] * ivar);
    }
}

// K3: direct shifted cross-correlation, 121 shifts.
// Block = 128 threads = (4 row-lanes interleaved) x (32 col-groups of 16 cols).
// Grid = 32 images x 32 chunks of 16 rows. Template ring tr[16][548] (pad 548: bank-conflict-free
// since 548 mod 32 = 4 and lane rg interleave spreads quads across all banks).
__global__ __launch_bounds__(128, 2) void k_ncc(const float* __restrict__ fr, const float* __restrict__ tpl,
                                                const double* __restrict__ stats, float* __restrict__ partial){
    int b = blockIdx.x >> 5, chunk = blockIdx.x & 31;
    const float* img = fr + (size_t)b * NPIX;
    float mean = (float)stats[0];
    __shared__ float tr[16][548];
    __shared__ float wred[2][121];
    int i0 = chunk << 4;
    int tid = threadIdx.x;
    // prefill ring with unwrapped rows i0-5 .. i0+10
    for (int idx = tid; idx < 16*544; idx += 128){
        int r = idx / 544, k = idx - r*544;
        int rowu = i0 - 5 + r;
        tr[rowu & 15][k] = tpl[(((rowu + 512) & 511) << 9) | ((k - 16) & 511)] - mean;
    }
    __syncthreads();
    int rg = tid & 3;                 // row-lane (interleaved for LDS bank spread)
    int cg = tid >> 2;                // 0..31 col-group
    int j0 = cg << 4;
    float acc[11][11];
    #pragma unroll
    for (int a = 0; a < 11; ++a)
        #pragma unroll
        for (int c = 0; c < 11; ++c) acc[a][c] = 0.f;
    #pragma unroll 1
    for (int k = 0; k < 4; ++k){
        int i = i0 + 4*k + rg;        // 0..511, no wrap needed
        float x[16];
        #pragma unroll
        for (int q = 0; q < 4; ++q)
            *(float4*)&x[4*q] = *(const float4*)&img[(i<<9) + j0 + 4*q];
        #pragma unroll
        for (int s0 = 0; s0 < 11; ++s0){
            int rowt = i + 5 - s0;     // unwrapped; ring & 15 valid (window of 14 <= 16)
            const float* trow = tr[rowt & 15];
            float tv[32];
            #pragma unroll
            for (int q = 0; q < 8; ++q)
                *(float4*)&tv[4*q] = *(const float4*)&trow[j0 + 8 + 4*q];   // t[rowt][j0-8 .. j0+23]
            #pragma unroll
            for (int s1 = 0; s1 < 11; ++s1)
                #pragma unroll
                for (int c = 0; c < 16; ++c)
                    acc[s0][s1] += x[c] * tv[c + 13 - s1];   // t[rowt][j0+c+5-s1]
        }
        __syncthreads();
        if (k < 3){
            // stage next 4 rows: i0+11+4k .. i0+14+4k (replace oldest 4)
            for (int idx = tid; idx < 4*544; idx += 128){
                int r = idx / 544, kk = idx - r*544;
                int rowu = i0 + 11 + 4*k + r;
                tr[rowu & 15][kk] = tpl[(((rowu) & 511) << 9) | ((kk - 16) & 511)] - mean;
            }
        }
        __syncthreads();
    }
    int lane = tid & 63, wv = tid >> 6;
    #pragma unroll 1
    for (int e = 0; e < 121; ++e){
        float v = acc[e/11][e%11];
        v += __shfl_down(v, 32); v += __shfl_down(v, 16); v += __shfl_down(v, 8);
        v += __shfl_down(v, 4);  v += __shfl_down(v, 2);  v += __shfl_down(v, 1);
        if (lane == 0) wred[wv][e] = v;
    }
    __syncthreads();
    if (tid < 121)
        partial[(size_t)(b*32 + chunk)*121 + tid] = wred[0][tid] + wred[1][tid];
}

// K4: ncc, argmax, log-parabola subpixel -> shifts (double), c2 coefficient
__global__ __launch_bounds__(128) void k_shifts(const float* __restrict__ partial, const double* __restrict__ den,
                                                const double* __restrict__ snn_part, double* __restrict__ shx,
                                                double* __restrict__ shy, float* __restrict__ c2){
    int b = blockIdx.x;
    __shared__ double l[121], nc[121];
    for (int e = threadIdx.x; e < 121; e += 128){
        double s = 0.0;
        for (int c = 0; c < 32; ++c) s += (double)partial[(size_t)(b*32 + c)*121 + e];
        double nom = fabs(s);
        double v = nom / den[b*121 + e];
        if (v != v) v = 0.0;
        nc[e] = v;
        l[e] = log(v);
    }
    __syncthreads();
    if (threadIdx.x == 0){
        int am = 0; double best = nc[0];
        for (int e = 1; e < 121; ++e) if (nc[e] > best){ best = nc[e]; am = e; }
        int u = am / 11, v = am % 11;
        double sx = -(double)(u - 5), sy = -(double)(v - 5);
        int um1 = u - 1; if (um1 < 0) um1 += 11; if (um1 > 10) um1 = 10;
        int up1 = u + 1; if (up1 > 10) up1 = 10;
        int vm1 = v - 1; if (vm1 < 0) vm1 += 11; if (vm1 > 10) vm1 = 10;
        int vp1 = v + 1; if (vp1 > 10) vp1 = 10;
        double l0x4 = 4.0 * l[u*11 + v];
        double lm = l[um1*11 + v], lp = l[up1*11 + v];
        sx -= (lm - lp) / (2.0*lm - l0x4 + 2.0*lp);
        double lm2 = l[u*11 + vm1], lp2 = l[u*11 + vp1];
        sy -= (lm2 - lp2) / (2.0*lm2 - l0x4 + 2.0*lp2);
        shx[b] = sx; shy[b] = sy;
        double snn = 0.0;
        for (int c = 0; c < 8; ++c) snn += snn_part[b*8 + c];
        double kx = sin(PI_D * sx) / 512.0, ky = sin(PI_D * sy) / 512.0;
        c2[b] = (float)(kx * ky * snn);
    }
}

__device__ inline double grekern(int t, double s){
    double u = (double)t - s;
    if (u > 256.0) u -= 512.0;
    double a = PI_D * u / 512.0;
    double sp = sin(a);
    double D;
    if (fabs(sp) < 1e-12) D = cos(PI_D * u) / cos(a);     // u ~ 0
    else D = sin(PI_D * u) / (512.0 * sp);
    return D * cos(a);
}

// K4b: real parts of the Dirichlet shift kernels (imag part handled analytically via c2)
__global__ __launch_bounds__(256) void k_tables(const double* __restrict__ shx, const double* __restrict__ shy,
                                                float* __restrict__ ary, float* __restrict__ arx){
    int b = blockIdx.x;
    double sx = shx[b], sy = shy[b];
    for (int t = threadIdx.x; t < 512; t += 256){
        arx[(b<<9) + t] = (float)grekern(t, sx);
        ary[(b<<9) + t] = (float)grekern(t, sy);
    }
}

// K5/K6: out[r][p] = sum_m in[r][m] * kern[(p-m)&511]   (real circulant matmul), optional parity correction
template<int CORR>
__global__ __launch_bounds__(256) void k_rowcirc(const float* __restrict__ src, int src_local,
                                                 const float* __restrict__ kern_all,
                                                 float* __restrict__ dst,
                                                 const float* __restrict__ c2, int c0){
    int lb = blockIdx.x >> 5, blk = blockIdx.x & 31;
    int b = c0 + lb;
    const float* in = src + (size_t)(src_local ? lb : b) * NPIX;
    const float* kern = kern_all + ((size_t)b << 9);
    float* out = dst + (size_t)b * NPIX;
    __shared__ float kd[1024];
    __shared__ float Xr[16][512];
    int r0 = blk << 4;
    for (int idx = threadIdx.x; idx < 1024; idx += 256) kd[idx] = kern[idx & 511];
    for (int idx = threadIdx.x; idx < 8192; idx += 256){
        int rr = idx >> 9;
        Xr[rr][idx & 511] = in[((size_t)(r0 + rr) << 9) + (idx & 511)];
    }
    __syncthreads();
    int rg = threadIdx.x >> 6;
    int p0 = (threadIdx.x & 63) << 3;
    float acc[4][8];
    #pragma unroll
    for (int a = 0; a < 4; ++a)
        #pragma unroll
        for (int c = 0; c < 8; ++c) acc[a][c] = 0.f;
    for (int m = 0; m < 512; m += 4){
        int base = p0 - m + 508;                  // 4-aligned, in [0,1012]
        float4 kq0 = *(const float4*)&kd[base];
        float4 kq1 = *(const float4*)&kd[base + 4];
        float4 kq2 = *(const float4*)&kd[base + 8];
        float kw[12] = {kq0.x,kq0.y,kq0.z,kq0.w, kq1.x,kq1.y,kq1.z,kq1.w, kq2.x,kq2.y,kq2.z,kq2.w};
        #pragma unroll
        for (int rr = 0; rr < 4; ++rr){
            float4 xv = *(const float4*)&Xr[rg*4 + rr][m];
            float xm[4] = {xv.x, xv.y, xv.z, xv.w};
            #pragma unroll
            for (int mi = 0; mi < 4; ++mi)
                #pragma unroll
                for (int pp = 0; pp < 8; ++pp)
                    acc[rr][pp] += xm[mi] * kw[pp + 4 - mi];
        }
    }
    float cc = CORR ? c2[b] : 0.f;
    #pragma unroll
    for (int rr = 0; rr < 4; ++rr){
        int q = r0 + rg*4 + rr;
        float vals[8];
        #pragma unroll
        for (int pp = 0; pp < 8; ++pp){
            float v = acc[rr][pp];
            if (CORR){
                int p = p0 + pp;
                v -= ((q + p) & 1) ? -cc : cc;    // out -= c2 * (-1)^(p+q)
            }
            vals[pp] = v;
        }
        float4 o0 = {vals[0], vals[1], vals[2], vals[3]};
        float4 o1 = {vals[4], vals[5], vals[6], vals[7]};
        *(float4*)&out[((size_t)q << 9) + p0] = o0;
        *(float4*)&out[((size_t)q << 9) + p0 + 4] = o1;
    }
}

// transpose 512x512 (YRe in d_out -> YT in ws)
__global__ __launch_bounds__(256) void k_transpose(const float* __restrict__ in, float* __restrict__ out, int c0){
    int lb = blockIdx.x >> 8, tb = blockIdx.x & 255;
    int b = c0 + lb;
    int tx = (tb & 15) << 5, ty = ((tb >> 4) & 15) << 5;
    const float* src = in + (size_t)b * NPIX;
    float* dst = out + (size_t)lb * NPIX;
    __shared__ float tile[32][33];
    int col = threadIdx.x & 31, rw = threadIdx.x >> 5;
    #pragma unroll
    for (int k = 0; k < 4; ++k){
        int ry = rw + k*8;
        tile[ry][col] = src[((size_t)(ty + ry) << 9) + tx + col];
    }
    __syncthreads();
    #pragma unroll
    for (int k = 0; k < 4; ++k){
        int ry = rw + k*8;
        dst[((size_t)(tx + ry) << 9) + ty + col] = tile[col][ry];
    }
}

extern "C" void kernel_launch(void* const* d_in, const int* in_sizes, int n_in,
                              void* d_out, int out_size, void* d_ws, size_t ws_size,
                              hipStream_t stream){
    (void)in_sizes; (void)n_in; (void)out_size;
    const float* fr  = (const float*)d_in[0];   // (1,32,512,512,1) f32
    const float* tpl = (const float*)d_in[1];   // (512,512) f32
    float* out = (float*)d_out;                 // (32, 512*512) f32
    char* ws = (char*)d_ws;

    double* stats  = (double*)(ws + 0);
    double* spart  = (double*)(ws + 64);
    double* den    = (double*)(ws + 2048);
    double* snnp   = (double*)(ws + 33280);
    double* shx    = (double*)(ws + 35328);
    double* shy    = (double*)(ws + 35584);
    float*  c2     = (float*) (ws + 35840);
    float*  part   = (float*) (ws + 36096);
    float*  ary    = (float*) (ws + 532480);
    float*  arx    = (float*) (ws + 598016);
    float*  csum   = (float*) (ws + 663552);
    float*  csum2  = (float*) (ws + 1187840);
    float*  yt     = (float*) (ws + 2097152);

    long long ytcap = ((long long)ws_size - 2097152) / ((long long)NPIX * 4);
    int cb = (int)ytcap; if (cb > 32) cb = 32; if (cb < 1) cb = 1;

    k_stats_part<<<64, 256, 0, stream>>>(tpl, spart);
    k_stats_final<<<1, 64, 0, stream>>>(spart, stats);
    k_colsums<<<256, 256, 0, stream>>>(fr, csum, csum2, snnp);
    k_winfin<<<32, 256, 0, stream>>>(fr, csum, csum2, stats, den);
    k_ncc<<<1024, 128, 0, stream>>>(fr, tpl, stats, part);
    k_shifts<<<32, 128, 0, stream>>>(part, den, snnp, shx, shy, c2);
    k_tables<<<32, 256, 0, stream>>>(shx, shy, ary, arx);

    for (int c0 = 0; c0 < 32; c0 += cb){
        int nb = (32 - c0 < cb) ? (32 - c0) : cb;
        // stage 1: YRe[m][q] = sum_n x[m][n] * gyRe[(q-n)&511]   (stored in d_out region of batch)
        k_rowcirc<0><<<nb*32, 256, 0, stream>>>(fr, 0, ary, out, (const float*)nullptr, c0);
        // transpose YRe -> YT
        k_transpose<<<nb*256, 256, 0, stream>>>(out, yt, c0);
        // stage 2: out[q*512+p] = sum_m YT[q][m] * gxRe[(p-m)&511]  - c2*(-1)^(p+q)
        k_rowcirc<1><<<nb*32, 256, 0, stream>>>(yt, 1, arx, out, c2, c0);
    }
}